// Round 1
// baseline (434.256 us; speedup 1.0000x reference)
//
#include <hip/hip_runtime.h>
#include <hip/hip_bf16.h>
#include <cstdint>

// ---------- types ----------
typedef __bf16 bf16x8 __attribute__((ext_vector_type(8)));
typedef __bf16 bf16x4 __attribute__((ext_vector_type(4)));
typedef float  f32x4  __attribute__((ext_vector_type(4)));

// ---------- fp32 -> bf16 convert (vectorized) ----------
__global__ void cvt_f32_bf16(const float* __restrict__ src, __bf16* __restrict__ dst, int n) {
    int i = (blockIdx.x * blockDim.x + threadIdx.x) * 4;
    if (i + 3 < n) {
        float4 v = *reinterpret_cast<const float4*>(src + i);
        bf16x4 o;
        o.x = (__bf16)v.x; o.y = (__bf16)v.y; o.z = (__bf16)v.z; o.w = (__bf16)v.w;
        *reinterpret_cast<bf16x4*>(dst + i) = o;
    }
}

// ---------- concat bq|bk|bv into one 2560-float buffer ----------
__global__ void concat_bias(const float* __restrict__ bq, const float* __restrict__ bk,
                            const float* __restrict__ bv, float* __restrict__ dst) {
    int t = blockIdx.x * blockDim.x + threadIdx.x;
    if (t < 2048)      dst[t] = bq[t];
    else if (t < 2304) dst[t] = bk[t - 2048];
    else if (t < 2560) dst[t] = bv[t - 2304];
}

// ---------- GEMM: C[m,n] = sum_k A[m,k]*B[n,k] (+bias[n]), bf16 in / fp32 out ----------
// 128x128 tile, BK=32, 4 waves (2x2), 16x16x32 MFMA. Reg-staged LDS (round 0 simple).
template<bool BIAS>
__global__ __launch_bounds__(256)
void gemm_bt(const __bf16* __restrict__ A, const __bf16* __restrict__ B,
             const float* __restrict__ bias, float* __restrict__ C,
             int M, int N, int K) {
    __shared__ __align__(16) __bf16 As[128 * 32];
    __shared__ __align__(16) __bf16 Bs[128 * 32];
    const int tid  = threadIdx.x;
    const int wave = tid >> 6, lane = tid & 63, lg = lane >> 4, ll = lane & 15;
    const int wr = wave >> 1, wc = wave & 1;
    const int bm = blockIdx.y, bn = blockIdx.x;
    const __bf16* Ab = A + (size_t)bm * 128 * K;
    const __bf16* Bb = B + (size_t)bn * 128 * K;

    f32x4 acc[4][4];
    for (int m = 0; m < 4; ++m)
        for (int n = 0; n < 4; ++n)
            acc[m][n] = f32x4{0.f, 0.f, 0.f, 0.f};

    const int row0 = tid >> 2;          // 0..63
    const int cs   = (tid & 3) * 8;     // 0,8,16,24

    for (int k0 = 0; k0 < K; k0 += 32) {
        // prefetch to regs (overlaps with previous tile's MFMA via scheduler)
        bf16x8 a0 = *reinterpret_cast<const bf16x8*>(Ab + (size_t)row0 * K + k0 + cs);
        bf16x8 a1 = *reinterpret_cast<const bf16x8*>(Ab + (size_t)(row0 + 64) * K + k0 + cs);
        bf16x8 b0 = *reinterpret_cast<const bf16x8*>(Bb + (size_t)row0 * K + k0 + cs);
        bf16x8 b1 = *reinterpret_cast<const bf16x8*>(Bb + (size_t)(row0 + 64) * K + k0 + cs);
        __syncthreads();   // previous iteration's LDS reads done
        *reinterpret_cast<bf16x8*>(&As[row0 * 32 + cs])        = a0;
        *reinterpret_cast<bf16x8*>(&As[(row0 + 64) * 32 + cs]) = a1;
        *reinterpret_cast<bf16x8*>(&Bs[row0 * 32 + cs])        = b0;
        *reinterpret_cast<bf16x8*>(&Bs[(row0 + 64) * 32 + cs]) = b1;
        __syncthreads();

        bf16x8 af[4], bfr[4];
        for (int m = 0; m < 4; ++m)
            af[m] = *reinterpret_cast<const bf16x8*>(&As[(wr * 64 + m * 16 + ll) * 32 + lg * 8]);
        for (int n = 0; n < 4; ++n)
            bfr[n] = *reinterpret_cast<const bf16x8*>(&Bs[(wc * 64 + n * 16 + ll) * 32 + lg * 8]);
        for (int m = 0; m < 4; ++m)
            for (int n = 0; n < 4; ++n)
                acc[m][n] = __builtin_amdgcn_mfma_f32_16x16x32_bf16(af[m], bfr[n], acc[m][n], 0, 0, 0);
    }

    for (int m = 0; m < 4; ++m)
        for (int n = 0; n < 4; ++n) {
            const int col = bn * 128 + wc * 64 + n * 16 + ll;
            const float bv = BIAS ? bias[col] : 0.f;
            for (int r = 0; r < 4; ++r) {
                const int rowg = bm * 128 + wr * 64 + m * 16 + lg * 4 + r;
                C[(size_t)rowg * N + col] = acc[m][n][r] + bv;
            }
        }
}

// ---------- RoPE + layout transform ----------
// qkv: (B*L, 2560) fp32.  Writes:
//   qT (b,h,l,d) bf16  with 1/sqrt(D) folded in
//   kT (b,kv,l,d) bf16
//   vT (b,kv,d,l) bf16  (transposed so PV B-fragments are contiguous)
__global__ void rope_kernel(const float* __restrict__ qkv, const float* __restrict__ cosb,
                            const float* __restrict__ sinb, __bf16* __restrict__ qT,
                            __bf16* __restrict__ kT, __bf16* __restrict__ vT) {
    const int row = blockIdx.x;          // b*2048 + l
    const int b = row >> 11, l = row & 2047;
    const int t = threadIdx.x;
    const float* r = qkv + (size_t)row * 2560;
    const float qscale = 0.08838834764831845f;   // 1/sqrt(128)

    for (int idx = t; idx < 2048; idx += 256) {
        const int h = idx >> 7, d = idx & 127;
        const float v = r[idx];
        const float partner = (d < 64) ? -r[h * 128 + d + 64] : r[h * 128 + d - 64];
        const float c = cosb[l * 128 + d], s = sinb[l * 128 + d];
        const float out = v * c + partner * s;
        qT[(((size_t)(b * 16 + h)) * 2048 + l) * 128 + d] = (__bf16)(out * qscale);
    }
    {   // exactly one iteration: 256 threads == 256 K elems
        const int idx = t;
        const int kvh = idx >> 7, d = idx & 127;
        const float v = r[2048 + idx];
        const float partner = (d < 64) ? -r[2048 + kvh * 128 + d + 64]
                                       : -0.f + r[2048 + kvh * 128 + d - 64];
        const float c = cosb[l * 128 + d], s = sinb[l * 128 + d];
        const float out = v * c + partner * s;
        kT[(((size_t)(b * 2 + kvh)) * 2048 + l) * 128 + d] = (__bf16)out;
        const float vv = r[2304 + idx];
        vT[(((size_t)(b * 2 + kvh)) * 128 + d) * 2048 + l] = (__bf16)vv;
    }
}

// ---------- causal GQA flash attention ----------
// grid (L/64, H, B), 256 threads = 4 waves, each wave owns 16 q rows.
// KV tile = 64 keys. K_lds [64][136] (padded), Vt_lds [128][72] (padded, d-major),
// P relayout through per-wave LDS [16][72].
__global__ __launch_bounds__(256)
void attn_kernel(const __bf16* __restrict__ qT, const __bf16* __restrict__ kT,
                 const __bf16* __restrict__ vT, __bf16* __restrict__ attnb) {
    const int qb = blockIdx.x, h = blockIdx.y, b = blockIdx.z;
    const int kv = h >> 3;   // G = 8
    const int tid = threadIdx.x, wave = tid >> 6, lane = tid & 63, lg = lane >> 4, ll = lane & 15;

    __shared__ __align__(16) __bf16 Kl[64 * 136];
    __shared__ __align__(16) __bf16 Vl[128 * 72];
    __shared__ __align__(16) __bf16 Pl[4][16 * 72];

    const int q0 = qb * 64 + wave * 16;
    const __bf16* qbase = qT + ((size_t)((b * 16 + h) * 2048) + q0 + ll) * 128;
    bf16x8 qf[4];
    for (int kk = 0; kk < 4; ++kk)
        qf[kk] = *reinterpret_cast<const bf16x8*>(qbase + kk * 32 + lg * 8);

    f32x4 o[8];
    for (int nd = 0; nd < 8; ++nd) o[nd] = f32x4{0.f, 0.f, 0.f, 0.f};
    float mrow[4] = {-3e38f, -3e38f, -3e38f, -3e38f};
    float srow[4] = {0.f, 0.f, 0.f, 0.f};

    const __bf16* kbase = kT + (size_t)((b * 2 + kv) * 2048) * 128;
    const __bf16* vbase = vT + (size_t)((b * 2 + kv) * 128) * 2048;
    const int ntiles = qb + 1;

    for (int t = 0; t < ntiles; ++t) {
        const int j0 = t * 64;
        __syncthreads();  // previous tile's PV reads done before overwrite
        // stage K tile [64 keys][128 d] -> Kl[key][d] (row stride 136)
        for (int i = 0; i < 4; ++i) {
            const int li = i * 256 + tid;
            const int key = li >> 4, dd = (li & 15) * 8;
            bf16x8 v = *reinterpret_cast<const bf16x8*>(kbase + (size_t)(j0 + key) * 128 + dd);
            *reinterpret_cast<bf16x8*>(&Kl[key * 136 + dd]) = v;
        }
        // stage V^T tile [128 d][64 keys] -> Vl[d][key] (row stride 72)
        for (int i = 0; i < 4; ++i) {
            const int li = i * 256 + tid;
            const int d = li >> 3, ks = (li & 7) * 8;
            bf16x8 v = *reinterpret_cast<const bf16x8*>(vbase + (size_t)d * 2048 + j0 + ks);
            *reinterpret_cast<bf16x8*>(&Vl[d * 72 + ks]) = v;
        }
        __syncthreads();

        // S = Q K^T  (scale already folded into Q)
        f32x4 s[4];
        for (int n = 0; n < 4; ++n) s[n] = f32x4{0.f, 0.f, 0.f, 0.f};
        for (int kk = 0; kk < 4; ++kk)
            for (int n = 0; n < 4; ++n) {
                bf16x8 kf = *reinterpret_cast<const bf16x8*>(&Kl[(n * 16 + ll) * 136 + kk * 32 + lg * 8]);
                s[n] = __builtin_amdgcn_mfma_f32_16x16x32_bf16(qf[kk], kf, s[n], 0, 0, 0);
            }

        // causal mask + online softmax (rows live in 16-lane groups)
        for (int r = 0; r < 4; ++r) {
            const int qrow = q0 + lg * 4 + r;
            float tmax = -3e38f;
            for (int n = 0; n < 4; ++n) {
                const int col = j0 + n * 16 + ll;
                float v = s[n][r];
                v = (col > qrow) ? -3e38f : v;
                s[n][r] = v;
                tmax = fmaxf(tmax, v);
            }
            for (int off = 1; off < 16; off <<= 1)
                tmax = fmaxf(tmax, __shfl_xor(tmax, off));
            const float mnew = fmaxf(mrow[r], tmax);
            const float scl = __expf(mrow[r] - mnew);
            mrow[r] = mnew;
            float rs = 0.f;
            for (int n = 0; n < 4; ++n) {
                const float p = __expf(s[n][r] - mnew);
                s[n][r] = p;
                rs += p;
            }
            for (int off = 1; off < 16; off <<= 1)
                rs += __shfl_xor(rs, off);
            srow[r] = srow[r] * scl + rs;
            for (int nd = 0; nd < 8; ++nd) o[nd][r] *= scl;
        }

        // P -> per-wave LDS (relayout for A-fragment)
        for (int n = 0; n < 4; ++n)
            for (int r = 0; r < 4; ++r)
                Pl[wave][(lg * 4 + r) * 72 + n * 16 + ll] = (__bf16)s[n][r];
        __syncthreads();

        // O += P V   (P: 16x64, V: 64x128)
        for (int kk = 0; kk < 2; ++kk) {
            bf16x8 pf = *reinterpret_cast<const bf16x8*>(&Pl[wave][ll * 72 + kk * 32 + lg * 8]);
            for (int nd = 0; nd < 8; ++nd) {
                bf16x8 vf = *reinterpret_cast<const bf16x8*>(&Vl[(nd * 16 + ll) * 72 + kk * 32 + lg * 8]);
                o[nd] = __builtin_amdgcn_mfma_f32_16x16x32_bf16(pf, vf, o[nd], 0, 0, 0);
            }
        }
    }

    // epilogue: normalize and store to (B, L, H*D) bf16
    for (int r = 0; r < 4; ++r) {
        const int qrow = q0 + lg * 4 + r;
        const float inv = 1.f / srow[r];
        for (int nd = 0; nd < 8; ++nd)
            attnb[((size_t)(b * 2048) + qrow) * 2048 + h * 128 + nd * 16 + ll] = (__bf16)(o[nd][r] * inv);
    }
}

// ---------- host launch ----------
extern "C" void kernel_launch(void* const* d_in, const int* in_sizes, int n_in,
                              void* d_out, int out_size, void* d_ws, size_t ws_size,
                              hipStream_t stream) {
    const float* x    = (const float*)d_in[0];
    const float* cosb = (const float*)d_in[1];
    const float* sinb = (const float*)d_in[2];
    const float* wq   = (const float*)d_in[3];
    const float* bq   = (const float*)d_in[4];
    const float* wk   = (const float*)d_in[5];
    const float* bk   = (const float*)d_in[6];
    const float* wv   = (const float*)d_in[7];
    const float* bv   = (const float*)d_in[8];
    const float* wo   = (const float*)d_in[9];
    float* out = (float*)d_out;

    char* ws = (char*)d_ws;
    // workspace layout (bytes)
    __bf16* xb    = (__bf16*)(ws);                         // 16,777,216  (later reused as attnb)
    __bf16* wb    = (__bf16*)(ws + 16777216);              // 10,485,760  (wq|wk|wv rows, 2560x2048)
    __bf16* wob   = (__bf16*)(ws + 27262976);              //  8,388,608
    float*  biasc = (float*) (ws + 35651584);              //     16,384 (2560 used)
    float*  qkvr  = (float*) (ws + 35667968);              // 41,943,040 (4096x2560)
    __bf16* qTp   = (__bf16*)(ws + 77611008);              // 16,777,216
    __bf16* kTp   = (__bf16*)(ws + 94388224);              //  2,097,152
    __bf16* vTp   = (__bf16*)(ws + 96485376);              //  2,097,152  -> total ~98.6 MB

    // 1) convert to bf16
    cvt_f32_bf16<<<8192, 256, 0, stream>>>(x,  xb, 8388608);
    cvt_f32_bf16<<<4096, 256, 0, stream>>>(wq, wb, 4194304);
    cvt_f32_bf16<<<512,  256, 0, stream>>>(wk, wb + 4194304, 524288);
    cvt_f32_bf16<<<512,  256, 0, stream>>>(wv, wb + 4718592, 524288);
    cvt_f32_bf16<<<4096, 256, 0, stream>>>(wo, wob, 4194304);
    concat_bias<<<10, 256, 0, stream>>>(bq, bk, bv, biasc);

    // 2) fused QKV GEMM: (4096x2048) x (2560x2048)^T + bias -> fp32
    gemm_bt<true><<<dim3(20, 32), 256, 0, stream>>>(xb, wb, biasc, qkvr, 4096, 2560, 2048);

    // 3) RoPE + layout
    rope_kernel<<<4096, 256, 0, stream>>>(qkvr, cosb, sinb, qTp, kTp, vTp);

    // 4) flash attention -> attnb (reuses xb region, bf16 (B,L,H*D))
    attn_kernel<<<dim3(32, 16, 2), 256, 0, stream>>>(qTp, kTp, vTp, xb);

    // 5) output GEMM: (4096x2048) x (2048x2048)^T -> fp32 d_out
    gemm_bt<false><<<dim3(16, 32), 256, 0, stream>>>(xb, wob, nullptr, out, 4096, 2048, 2048);
}

// Round 2
// 256.926 us; speedup vs baseline: 1.6902x; 1.6902x over previous
//
#include <hip/hip_runtime.h>
#include <hip/hip_bf16.h>
#include <cstdint>

// ---------- types ----------
typedef __bf16 bf16x8 __attribute__((ext_vector_type(8)));
typedef __bf16 bf16x4 __attribute__((ext_vector_type(4)));
typedef float  f32x4  __attribute__((ext_vector_type(4)));
typedef __attribute__((address_space(3))) __bf16 lds_bf16;
typedef __attribute__((address_space(1))) const __bf16 gl_bf16;

// ---------- fp32 -> bf16 convert (vectorized) ----------
__global__ void cvt_f32_bf16(const float* __restrict__ src, __bf16* __restrict__ dst, int n) {
    int i = (blockIdx.x * blockDim.x + threadIdx.x) * 4;
    if (i + 3 < n) {
        float4 v = *reinterpret_cast<const float4*>(src + i);
        bf16x4 o;
        o.x = (__bf16)v.x; o.y = (__bf16)v.y; o.z = (__bf16)v.z; o.w = (__bf16)v.w;
        *reinterpret_cast<bf16x4*>(dst + i) = o;
    }
}

// ---------- concat bq|bk|bv into one 2560-float buffer ----------
__global__ void concat_bias(const float* __restrict__ bq, const float* __restrict__ bk,
                            const float* __restrict__ bv, float* __restrict__ dst) {
    int t = blockIdx.x * blockDim.x + threadIdx.x;
    if (t < 2048)      dst[t] = bq[t];
    else if (t < 2304) dst[t] = bk[t - 2048];
    else if (t < 2560) dst[t] = bv[t - 2304];
}

// ---------- GEMM: C[m,n] = sum_k A[m,k]*B[n,k] (+bias[n]), bf16 in / fp32 out ----------
// m97 structure: 128x128 tile, BK=32, 4 waves (2x2), 16x16x32 MFMA,
// global_load_lds width-16 staging, 2 barriers per K-step.
template<bool BIAS>
__global__ __launch_bounds__(256)
void gemm_bt(const __bf16* __restrict__ A, const __bf16* __restrict__ B,
             const float* __restrict__ bias, float* __restrict__ C,
             int M, int N, int K) {
    __shared__ __align__(16) __bf16 As[128 * 32];
    __shared__ __align__(16) __bf16 Bs[128 * 32];
    const int tid  = threadIdx.x;
    const int wave = tid >> 6, lane = tid & 63, lg = lane >> 4, ll = lane & 15;
    const int wr = wave >> 1, wc = wave & 1;
    const int bm = blockIdx.y, bn = blockIdx.x;
    const __bf16* Ab = A + (size_t)bm * 128 * K;
    const __bf16* Bb = B + (size_t)bn * 128 * K;

    lds_bf16* AsL = (lds_bf16*)As;   // addrspace(3) views, wave-uniform bases
    lds_bf16* BsL = (lds_bf16*)Bs;

    f32x4 acc[4][4];
    for (int m = 0; m < 4; ++m)
        for (int n = 0; n < 4; ++n)
            acc[m][n] = f32x4{0.f, 0.f, 0.f, 0.f};

    const int row0 = tid >> 2;          // 0..63
    const int cs   = (tid & 3) * 8;     // 0,8,16,24
    const size_t rstride = (size_t)row0 * K + cs;

    for (int k0 = 0; k0 < K; k0 += 32) {
        __syncthreads();   // previous iteration's LDS reads done
        // stage A/B tiles direct to LDS: lane l of wave w -> base + l*16B (linear layout)
        const __bf16* ga = Ab + rstride + k0;
        const __bf16* gb = Bb + rstride + k0;
        __builtin_amdgcn_global_load_lds((gl_bf16*)ga,                 AsL + wave * 512,        16, 0, 0);
        __builtin_amdgcn_global_load_lds((gl_bf16*)(ga + (size_t)64*K), AsL + 2048 + wave * 512, 16, 0, 0);
        __builtin_amdgcn_global_load_lds((gl_bf16*)gb,                 BsL + wave * 512,        16, 0, 0);
        __builtin_amdgcn_global_load_lds((gl_bf16*)(gb + (size_t)64*K), BsL + 2048 + wave * 512, 16, 0, 0);
        __syncthreads();   // compiler drains vmcnt before barrier

        bf16x8 af[4], bfr[4];
        for (int m = 0; m < 4; ++m)
            af[m] = *reinterpret_cast<const bf16x8*>(&As[(wr * 64 + m * 16 + ll) * 32 + lg * 8]);
        for (int n = 0; n < 4; ++n)
            bfr[n] = *reinterpret_cast<const bf16x8*>(&Bs[(wc * 64 + n * 16 + ll) * 32 + lg * 8]);
        for (int m = 0; m < 4; ++m)
            for (int n = 0; n < 4; ++n)
                acc[m][n] = __builtin_amdgcn_mfma_f32_16x16x32_bf16(af[m], bfr[n], acc[m][n], 0, 0, 0);
    }

    for (int m = 0; m < 4; ++m)
        for (int n = 0; n < 4; ++n) {
            const int col = bn * 128 + wc * 64 + n * 16 + ll;
            const float bv = BIAS ? bias[col] : 0.f;
            for (int r = 0; r < 4; ++r) {
                const int rowg = bm * 128 + wr * 64 + m * 16 + lg * 4 + r;
                C[(size_t)rowg * N + col] = acc[m][n][r] + bv;
            }
        }
}

// ---------- RoPE + layout transform ----------
__global__ void rope_kernel(const float* __restrict__ qkv, const float* __restrict__ cosb,
                            const float* __restrict__ sinb, __bf16* __restrict__ qT,
                            __bf16* __restrict__ kT, __bf16* __restrict__ vT) {
    const int row = blockIdx.x;          // b*2048 + l
    const int b = row >> 11, l = row & 2047;
    const int t = threadIdx.x;
    const float* r = qkv + (size_t)row * 2560;
    const float qscale = 0.08838834764831845f;   // 1/sqrt(128)

    for (int idx = t; idx < 2048; idx += 256) {
        const int h = idx >> 7, d = idx & 127;
        const float v = r[idx];
        const float partner = (d < 64) ? -r[h * 128 + d + 64] : r[h * 128 + d - 64];
        const float c = cosb[l * 128 + d], s = sinb[l * 128 + d];
        const float out = v * c + partner * s;
        qT[(((size_t)(b * 16 + h)) * 2048 + l) * 128 + d] = (__bf16)(out * qscale);
    }
    {   // exactly one iteration: 256 threads == 256 K elems
        const int idx = t;
        const int kvh = idx >> 7, d = idx & 127;
        const float v = r[2048 + idx];
        const float partner = (d < 64) ? -r[2048 + kvh * 128 + d + 64]
                                       : r[2048 + kvh * 128 + d - 64];
        const float c = cosb[l * 128 + d], s = sinb[l * 128 + d];
        const float out = v * c + partner * s;
        kT[(((size_t)(b * 2 + kvh)) * 2048 + l) * 128 + d] = (__bf16)out;
        const float vv = r[2304 + idx];
        vT[(((size_t)(b * 2 + kvh)) * 128 + d) * 2048 + l] = (__bf16)vv;
    }
}

// ---------- causal GQA flash attention ----------
// 1-D grid of 1024 blocks, heavy (large-qb) blocks dispatched FIRST.
// 4 waves x 16 q rows, KV tile = 64. XOR-swizzled unpadded LDS tiles
// (40 KB total -> 4 blocks/CU). Next tile's K/V prefetched into regs so
// global latency hides under QK+softmax+PV. 2 barriers per tile.
__global__ __launch_bounds__(256)
void attn_kernel(const __bf16* __restrict__ qT, const __bf16* __restrict__ kT,
                 const __bf16* __restrict__ vT, __bf16* __restrict__ attnb) {
    const int bx = blockIdx.x;
    const int qb = 31 - (bx >> 5);       // heavy blocks first
    const int hb = bx & 31;
    const int h = hb >> 1, b = hb & 1;
    const int kv = h >> 3;               // G = 8
    const int tid = threadIdx.x, wave = tid >> 6, lane = tid & 63, lg = lane >> 4, ll = lane & 15;

    __shared__ __align__(16) __bf16 Kl[64 * 128];     // [key][d], chunk^=(key&7)
    __shared__ __align__(16) __bf16 Vl[128 * 64];     // [d][key], chunk^=(d&7)
    __shared__ __align__(16) __bf16 Pl[4][16 * 64];   // per-wave [qrow][key], chunk^=(row&7)

    const int q0 = qb * 64 + wave * 16;
    const __bf16* qbase = qT + ((size_t)((b * 16 + h) * 2048) + q0 + ll) * 128;
    bf16x8 qf[4];
    for (int kk = 0; kk < 4; ++kk)
        qf[kk] = *reinterpret_cast<const bf16x8*>(qbase + kk * 32 + lg * 8);

    f32x4 o[8];
    for (int nd = 0; nd < 8; ++nd) o[nd] = f32x4{0.f, 0.f, 0.f, 0.f};
    float mrow[4] = {-3e38f, -3e38f, -3e38f, -3e38f};
    float srow[4] = {0.f, 0.f, 0.f, 0.f};

    const __bf16* kbase = kT + (size_t)((b * 2 + kv) * 2048) * 128;
    const __bf16* vbase = vT + (size_t)((b * 2 + kv) * 128) * 2048;
    const int ntiles = qb + 1;

    // per-thread staging coordinates (4 chunks K, 4 chunks V, 16B each)
    const int kkey[1] = {0};
    char* KlB = (char*)Kl;
    char* VlB = (char*)Vl;
    char* PlB = (char*)&Pl[wave][0];

    bf16x8 kr[4], vr[4];
    // prologue: load tile 0 and store to LDS
    {
        const int j0 = 0;
        #pragma unroll
        for (int i = 0; i < 4; ++i) {
            const int li = i * 256 + tid;
            const int key = li >> 4, c = li & 15;
            kr[i] = *reinterpret_cast<const bf16x8*>(kbase + (size_t)(j0 + key) * 128 + c * 8);
            const int dd = li >> 3, cv = li & 7;
            vr[i] = *reinterpret_cast<const bf16x8*>(vbase + (size_t)dd * 2048 + j0 + cv * 8);
        }
        #pragma unroll
        for (int i = 0; i < 4; ++i) {
            const int li = i * 256 + tid;
            const int key = li >> 4, c = li & 15;
            *reinterpret_cast<bf16x8*>(KlB + key * 256 + ((c ^ (key & 7)) << 4)) = kr[i];
            const int dd = li >> 3, cv = li & 7;
            *reinterpret_cast<bf16x8*>(VlB + dd * 128 + ((cv ^ (dd & 7)) << 4)) = vr[i];
        }
        __syncthreads();
    }

    for (int t = 0; t < ntiles; ++t) {
        // issue next tile's global loads (latency hides under compute below)
        if (t + 1 < ntiles) {
            const int j0 = (t + 1) * 64;
            #pragma unroll
            for (int i = 0; i < 4; ++i) {
                const int li = i * 256 + tid;
                const int key = li >> 4, c = li & 15;
                kr[i] = *reinterpret_cast<const bf16x8*>(kbase + (size_t)(j0 + key) * 128 + c * 8);
                const int dd = li >> 3, cv = li & 7;
                vr[i] = *reinterpret_cast<const bf16x8*>(vbase + (size_t)dd * 2048 + j0 + cv * 8);
            }
        }
        const int j0 = t * 64;

        // S = Q K^T  (scale folded into Q); swizzled K reads, conflict-free
        f32x4 s[4];
        for (int n = 0; n < 4; ++n) s[n] = f32x4{0.f, 0.f, 0.f, 0.f};
        #pragma unroll
        for (int kk = 0; kk < 4; ++kk)
            #pragma unroll
            for (int n = 0; n < 4; ++n) {
                const int row = n * 16 + ll;
                bf16x8 kf = *reinterpret_cast<const bf16x8*>(
                    KlB + row * 256 + (((kk * 4 + lg) ^ (ll & 7)) << 4));
                s[n] = __builtin_amdgcn_mfma_f32_16x16x32_bf16(qf[kk], kf, s[n], 0, 0, 0);
            }

        // causal mask + online softmax (rows live across 16-lane groups)
        #pragma unroll
        for (int r = 0; r < 4; ++r) {
            const int qrow = q0 + lg * 4 + r;
            float tmax = -3e38f;
            #pragma unroll
            for (int n = 0; n < 4; ++n) {
                const int col = j0 + n * 16 + ll;
                float v = s[n][r];
                v = (col > qrow) ? -3e38f : v;
                s[n][r] = v;
                tmax = fmaxf(tmax, v);
            }
            #pragma unroll
            for (int off = 1; off < 16; off <<= 1)
                tmax = fmaxf(tmax, __shfl_xor(tmax, off));
            const float mnew = fmaxf(mrow[r], tmax);
            const float scl = __expf(mrow[r] - mnew);
            mrow[r] = mnew;
            float rs = 0.f;
            #pragma unroll
            for (int n = 0; n < 4; ++n) {
                const float p = __expf(s[n][r] - mnew);
                s[n][r] = p;
                rs += p;
            }
            #pragma unroll
            for (int off = 1; off < 16; off <<= 1)
                rs += __shfl_xor(rs, off);
            srow[r] = srow[r] * scl + rs;
            for (int nd = 0; nd < 8; ++nd) o[nd][r] *= scl;
        }

        // P -> per-wave LDS (swizzled); no barrier needed (wave-private)
        #pragma unroll
        for (int n = 0; n < 4; ++n)
            #pragma unroll
            for (int r = 0; r < 4; ++r) {
                const int row = lg * 4 + r, col = n * 16 + ll;
                *reinterpret_cast<__bf16*>(
                    PlB + row * 128 + (((col >> 3) ^ (row & 7)) << 4) + (col & 7) * 2)
                    = (__bf16)s[n][r];
            }

        // O += P V
        #pragma unroll
        for (int kk = 0; kk < 2; ++kk) {
            bf16x8 pf = *reinterpret_cast<const bf16x8*>(
                PlB + ll * 128 + (((kk * 4 + lg) ^ (ll & 7)) << 4));
            #pragma unroll
            for (int nd = 0; nd < 8; ++nd) {
                const int row = nd * 16 + ll;
                bf16x8 vf = *reinterpret_cast<const bf16x8*>(
                    VlB + row * 128 + (((kk * 4 + lg) ^ (ll & 7)) << 4));
                o[nd] = __builtin_amdgcn_mfma_f32_16x16x32_bf16(pf, vf, o[nd], 0, 0, 0);
            }
        }

        __syncthreads();   // all waves done reading Kl/Vl
        if (t + 1 < ntiles) {
            #pragma unroll
            for (int i = 0; i < 4; ++i) {
                const int li = i * 256 + tid;
                const int key = li >> 4, c = li & 15;
                *reinterpret_cast<bf16x8*>(KlB + key * 256 + ((c ^ (key & 7)) << 4)) = kr[i];
                const int dd = li >> 3, cv = li & 7;
                *reinterpret_cast<bf16x8*>(VlB + dd * 128 + ((cv ^ (dd & 7)) << 4)) = vr[i];
            }
            __syncthreads();
        }
    }

    // epilogue: normalize and store to (B, L, H*D) bf16
    #pragma unroll
    for (int r = 0; r < 4; ++r) {
        const int qrow = q0 + lg * 4 + r;
        const float inv = 1.f / srow[r];
        #pragma unroll
        for (int nd = 0; nd < 8; ++nd)
            attnb[((size_t)(b * 2048) + qrow) * 2048 + h * 128 + nd * 16 + ll] = (__bf16)(o[nd][r] * inv);
    }
}

// ---------- host launch ----------
extern "C" void kernel_launch(void* const* d_in, const int* in_sizes, int n_in,
                              void* d_out, int out_size, void* d_ws, size_t ws_size,
                              hipStream_t stream) {
    const float* x    = (const float*)d_in[0];
    const float* cosb = (const float*)d_in[1];
    const float* sinb = (const float*)d_in[2];
    const float* wq   = (const float*)d_in[3];
    const float* bq   = (const float*)d_in[4];
    const float* wk   = (const float*)d_in[5];
    const float* bk   = (const float*)d_in[6];
    const float* wv   = (const float*)d_in[7];
    const float* bv   = (const float*)d_in[8];
    const float* wo   = (const float*)d_in[9];
    float* out = (float*)d_out;

    char* ws = (char*)d_ws;
    __bf16* xb    = (__bf16*)(ws);                         // 16,777,216  (later reused as attnb)
    __bf16* wb    = (__bf16*)(ws + 16777216);              // 10,485,760  (wq|wk|wv rows, 2560x2048)
    __bf16* wob   = (__bf16*)(ws + 27262976);              //  8,388,608
    float*  biasc = (float*) (ws + 35651584);              //     16,384 (2560 used)
    float*  qkvr  = (float*) (ws + 35667968);              // 41,943,040 (4096x2560)
    __bf16* qTp   = (__bf16*)(ws + 77611008);              // 16,777,216
    __bf16* kTp   = (__bf16*)(ws + 94388224);              //  2,097,152
    __bf16* vTp   = (__bf16*)(ws + 96485376);              //  2,097,152

    // 1) convert to bf16
    cvt_f32_bf16<<<8192, 256, 0, stream>>>(x,  xb, 8388608);
    cvt_f32_bf16<<<4096, 256, 0, stream>>>(wq, wb, 4194304);
    cvt_f32_bf16<<<512,  256, 0, stream>>>(wk, wb + 4194304, 524288);
    cvt_f32_bf16<<<512,  256, 0, stream>>>(wv, wb + 4718592, 524288);
    cvt_f32_bf16<<<4096, 256, 0, stream>>>(wo, wob, 4194304);
    concat_bias<<<10, 256, 0, stream>>>(bq, bk, bv, biasc);

    // 2) fused QKV GEMM: (4096x2048) x (2560x2048)^T + bias -> fp32
    gemm_bt<true><<<dim3(20, 32), 256, 0, stream>>>(xb, wb, biasc, qkvr, 4096, 2560, 2048);

    // 3) RoPE + layout
    rope_kernel<<<4096, 256, 0, stream>>>(qkvr, cosb, sinb, qTp, kTp, vTp);

    // 4) flash attention -> attnb (reuses xb region, bf16 (B,L,H*D))
    attn_kernel<<<1024, 256, 0, stream>>>(qTp, kTp, vTp, xb);

    // 5) output GEMM: (4096x2048) x (2048x2048)^T -> fp32 d_out
    gemm_bt<false><<<dim3(16, 32), 256, 0, stream>>>(xb, wob, nullptr, out, 4096, 2048, 2048);
}